// Round 5
// baseline (18181.133 us; speedup 1.0000x reference)
//
#include <hip/hip_runtime.h>

typedef unsigned short u16;
typedef _Float16 f16;
typedef f16 half8 __attribute__((ext_vector_type(8)));
typedef float float4v __attribute__((ext_vector_type(4)));

union HV { uint4 u; half8 h; u16 s[8]; };

__device__ __forceinline__ float h2f(u16 u) { union { u16 u; f16 h; } c; c.u = u; return (float)c.h; }
__device__ __forceinline__ u16 f2h(float f) { union { u16 u; f16 h; } c; c.h = (f16)f; return c.u; }

// ---- coherent (cross-XCD) access helpers: sc0 sc1 => operate at LLC, bypass XCD L2 ----
__device__ __forceinline__ void store_coh_u16(u16* p, unsigned v) {
  asm volatile("global_store_short %0, %1, off sc0 sc1" :: "v"(p), "v"(v) : "memory");
}
__device__ __forceinline__ void store_coh_u32(void* p, unsigned v) {
  asm volatile("global_store_dword %0, %1, off sc0 sc1" :: "v"(p), "v"(v) : "memory");
}
// single-instruction 8B store: [f32 payload | u32 epoch tag] — atomically visible
__device__ __forceinline__ void store_coh_f32_tag(float* p, float val, unsigned tag) {
  unsigned long long pk = (unsigned long long)__float_as_uint(val) |
                          ((unsigned long long)tag << 32);
  asm volatile("global_store_dwordx2 %0, %1, off sc0 sc1" :: "v"(p), "v"(pk) : "memory");
}

// ---------------- fp32 -> fp16 convert ----------------
__global__ void cvt_f32_f16(const float* __restrict__ s, u16* __restrict__ d, int n) {
  for (int i = blockIdx.x * blockDim.x + threadIdx.x; i < n; i += gridDim.x * blockDim.x)
    d[i] = f2h(s[i]);
}

// ---------------- GEMM: C[M][2048] = A[M][K] * B[2048][K]^T (fp16 in/out, fp32 accum) ----------
__global__ __launch_bounds__(256) void gemm_f16(const u16* __restrict__ A, const u16* __restrict__ B,
                                                u16* __restrict__ C, int K) {
  __shared__ u16 As[128][40];
  __shared__ u16 Bs[128][40];
  const int tid = threadIdx.x, lane = tid & 63, wid = tid >> 6;
  const int col = lane & 15, quad = lane >> 4;
  const int wm = (wid & 1) * 64, wn = (wid >> 1) * 64;
  const int n0 = blockIdx.x * 128;
  const int m0 = blockIdx.y * 128;
  float4v acc[4][4];
  #pragma unroll
  for (int i = 0; i < 4; ++i)
    #pragma unroll
    for (int j = 0; j < 4; ++j) acc[i][j] = (float4v){0.f, 0.f, 0.f, 0.f};

  const int srow = tid >> 2;
  const int schunk = (tid & 3) * 8;

  for (int k0 = 0; k0 < K; k0 += 32) {
    __syncthreads();
    #pragma unroll
    for (int r2 = 0; r2 < 2; ++r2) {
      int row = srow + 64 * r2;
      int kk = k0 + schunk;
      uint4 av = {0, 0, 0, 0}, bv = {0, 0, 0, 0};
      if (kk + 8 <= K) {
        av = *(const uint4*)(A + (size_t)(m0 + row) * K + kk);
        bv = *(const uint4*)(B + (size_t)(n0 + row) * K + kk);
      }
      *(uint4*)&As[row][schunk] = av;
      *(uint4*)&Bs[row][schunk] = bv;
    }
    __syncthreads();
    HV af[4], bf[4];
    #pragma unroll
    for (int i = 0; i < 4; ++i) af[i].u = *(const uint4*)&As[wm + i * 16 + col][quad * 8];
    #pragma unroll
    for (int j = 0; j < 4; ++j) bf[j].u = *(const uint4*)&Bs[wn + j * 16 + col][quad * 8];
    #pragma unroll
    for (int i = 0; i < 4; ++i)
      #pragma unroll
      for (int j = 0; j < 4; ++j)
        acc[i][j] = __builtin_amdgcn_mfma_f32_16x16x32_f16(af[i].h, bf[j].h, acc[i][j], 0, 0, 0);
  }
  #pragma unroll
  for (int i = 0; i < 4; ++i)
    #pragma unroll
    for (int j = 0; j < 4; ++j)
      #pragma unroll
      for (int r = 0; r < 4; ++r) {
        int m = m0 + wm + i * 16 + quad * 4 + r;
        int n = n0 + wn + j * 16 + col;
        C[(size_t)m * 2048 + n] = f2h(acc[i][j][r]);
      }
}

// ---------------- BatchNorm stats over 32000 rows ----------------
__global__ void bn_stats(const u16* __restrict__ C, float* __restrict__ acc) {
  int c = blockIdx.x * 256 + threadIdx.x;
  int r0 = blockIdx.y * 256;
  float s = 0.f, q = 0.f;
  for (int r = r0; r < r0 + 256; ++r) {
    float v = h2f(C[(size_t)r * 2048 + c]);
    s += v; q += v * v;
  }
  atomicAdd(&acc[2 * c], s);
  atomicAdd(&acc[2 * c + 1], q);
}

__global__ void bn_final(const float* __restrict__ acc, const float* __restrict__ g,
                         const float* __restrict__ b, float2* __restrict__ ss) {
  int c = blockIdx.x * 256 + threadIdx.x;
  float mean = acc[2 * c] * (1.f / 32000.f);
  float var = acc[2 * c + 1] * (1.f / 32000.f) - mean * mean;
  float sc = g[c] * rsqrtf(var + 1e-5f);
  float2 o; o.x = sc; o.y = b[c] - mean * sc;
  ss[c] = o;
}

// ---------------- persistent recurrence ----------------
// 2 independent domains x 32 blocks; domain d owns batches [16d,16d+16).
// Block beta owns 64 gate cols (32 h-cols). Wave kh: (phase A) K-slice
// [256kh,256kh+256) of U in VGPRs; (phase B) batch group [4kh,4kh+4).
//
// SYMMETRIC phase B (this round's change): all 4 waves write their K-partials
// to red[kh], S1, then EVERY wave reduces all 4 slots (redundant, parallel).
// MFMA C-layout puts batch row quad*4+r in lane-group quad, so wave v's lanes
// with quad==v hold the full gates for batches 4v..4v+3 -> wave v runs stats
// publish, gather-poll, LN, h stores, ack, and its OWN flag f2[block][v] for
// those batches. No idle waves; serial phase-B cost /4.
//
// Rounds per step: R1 stats via epoch-tagged 8B records (poll-gather, no
// flag); R2 h broadcast via per-wave flags (dwordx4 poll of [block][wave]).
// Safety: stats(t) published after S1 => all 4 waves' h loads(t) drained =>
// h(t) stores race-free vs h(t-1) loads. poll(t) requires all waves' flags =>
// red(t) reads complete before red(t+1) writes. pstats parity slot is 2
// epochs ahead of any reuse. Per-wave vmcnt(0) orders h stores before flag.
//
// pstats: [dom][phase][batch16][block32][s,tag,q,tag] f32
// flags:  [dom][block32][16] u32, waves use [block][0..3]
template <int OUT_F32>
__global__ __launch_bounds__(256, 1) void rec_kernel(
    const u16* __restrict__ w,      // [32*1000][2048] fp16 (pre-BN)
    const float2* __restrict__ ss,  // [2048] BN scale/shift
    const u16* __restrict__ U,      // [2048][1024] fp16
    u16* hbuf,                      // [32][1024] fp16 (current h)
    float* pstats,                  // [2][2][16][32][4] f32
    unsigned* flags,                // [2][32][16] u32
    u16* out16, float* out32) {
  const int tid = threadIdx.x, lane = tid & 63, kh = tid >> 6;
  const int d = blockIdx.x >> 5, beta = blockIdx.x & 31;
  const int col = lane & 15, quad = lane >> 4;
  const int act = (quad == kh);        // this wave's phase-B lanes
  const int bloc = kh * 4;             // this wave's batch group
  __shared__ float4v red[4][4][64];

  const int ja = beta * 32 + col;     // a-col group 0 (group 1 = +16)

  HV ufA0[8], ufA1[8], ufZ0[8], ufZ1[8];   // U fragments: 64 gate cols x K=256
  #pragma unroll
  for (int kk = 0; kk < 8; ++kk) {
    int k = kh * 256 + kk * 32 + quad * 8;
    ufA0[kk].u = *(const uint4*)(U + (size_t)ja * 1024 + k);
    ufA1[kk].u = *(const uint4*)(U + (size_t)(ja + 16) * 1024 + k);
    ufZ0[kk].u = *(const uint4*)(U + (size_t)(1024 + ja) * 1024 + k);
    ufZ1[kk].u = *(const uint4*)(U + (size_t)(1024 + ja + 16) * 1024 + k);
  }
  float2 ssA0 = ss[ja], ssA1 = ss[ja + 16];
  float2 ssZ0 = ss[1024 + ja], ssZ1 = ss[1024 + ja + 16];

  u16* hb = hbuf + (size_t)d * 16 * 1024;          // this domain's 16 h rows
  float* ps = pstats + (size_t)d * 4096;           // 2*16*32*4 floats
  unsigned* f2 = flags + (size_t)d * 512;          // 32 x 16 u32 (64B stride)

  const u16* aptr = hb + (size_t)col * 1024 + kh * 256 + quad * 8;

  float hreg[4][2] = {{0.f, 0.f}, {0.f, 0.f}, {0.f, 0.f}, {0.f, 0.f}};
  u16 wa0[4], wa1[4], wz0[4], wz1[4];              // w for CURRENT step
  if (act) {
    #pragma unroll
    for (int r = 0; r < 4; ++r) {
      const u16* wr = w + ((size_t)(d * 16 + bloc + r) * 1000 + 0) * 2048 + ja;
      wa0[r] = wr[0]; wa1[r] = wr[16]; wz0[r] = wr[1024]; wz1[r] = wr[1040];
    }
  }

  for (int t = 0; t < 1000; ++t) {
    const unsigned tag = (unsigned)t + 1u;
    // ---- phase A: coherent h load (8 x 16B) + partial-K MFMA ----
    HV af[8];
    asm volatile(
        "global_load_dwordx4 %0, %8, off sc0 sc1\n\t"
        "global_load_dwordx4 %1, %8, off offset:64  sc0 sc1\n\t"
        "global_load_dwordx4 %2, %8, off offset:128 sc0 sc1\n\t"
        "global_load_dwordx4 %3, %8, off offset:192 sc0 sc1\n\t"
        "global_load_dwordx4 %4, %8, off offset:256 sc0 sc1\n\t"
        "global_load_dwordx4 %5, %8, off offset:320 sc0 sc1\n\t"
        "global_load_dwordx4 %6, %8, off offset:384 sc0 sc1\n\t"
        "global_load_dwordx4 %7, %8, off offset:448 sc0 sc1\n\t"
        "s_waitcnt vmcnt(0)"
        : "=v"(af[0].u), "=v"(af[1].u), "=v"(af[2].u), "=v"(af[3].u),
          "=v"(af[4].u), "=v"(af[5].u), "=v"(af[6].u), "=v"(af[7].u)
        : "v"(aptr)
        : "memory");

    float4v aA0 = (float4v){0.f, 0.f, 0.f, 0.f};
    float4v aA1 = (float4v){0.f, 0.f, 0.f, 0.f};
    float4v aZ0 = (float4v){0.f, 0.f, 0.f, 0.f};
    float4v aZ1 = (float4v){0.f, 0.f, 0.f, 0.f};
    #pragma unroll
    for (int kk = 0; kk < 8; ++kk) {
      aA0 = __builtin_amdgcn_mfma_f32_16x16x32_f16(af[kk].h, ufA0[kk].h, aA0, 0, 0, 0);
      aA1 = __builtin_amdgcn_mfma_f32_16x16x32_f16(af[kk].h, ufA1[kk].h, aA1, 0, 0, 0);
      aZ0 = __builtin_amdgcn_mfma_f32_16x16x32_f16(af[kk].h, ufZ0[kk].h, aZ0, 0, 0, 0);
      aZ1 = __builtin_amdgcn_mfma_f32_16x16x32_f16(af[kk].h, ufZ1[kk].h, aZ1, 0, 0, 0);
    }
    red[kh][0][lane] = aA0; red[kh][1][lane] = aA1;
    red[kh][2][lane] = aZ0; red[kh][3][lane] = aZ1;
    __syncthreads();   // S1: all partials in LDS (all waves' h loads drained)

    // every wave reduces the other 3 slots (redundant across waves, parallel)
    {
      const int k1 = (kh + 1) & 3, k2 = (kh + 2) & 3, k3 = (kh + 3) & 3;
      aA0 += red[k1][0][lane] + red[k2][0][lane] + red[k3][0][lane];
      aA1 += red[k1][1][lane] + red[k2][1][lane] + red[k3][1][lane];
      aZ0 += red[k1][2][lane] + red[k2][2][lane] + red[k3][2][lane];
      aZ1 += red[k1][3][lane] + red[k2][3][lane] + red[k3][3][lane];
    }
    const int p = t & 1;
    u16 wn_a0[4], wn_a1[4], wn_z0[4], wn_z1[4];
    if (act) {
      // ---- R1 publish: tagged partial stats for this wave's 4 batches ----
      #pragma unroll
      for (int r = 0; r < 4; ++r) {
        float sv = aA0[r] + aA1[r] + aZ0[r] + aZ1[r];
        float qv = aA0[r] * aA0[r] + aA1[r] * aA1[r] + aZ0[r] * aZ0[r] + aZ1[r] * aZ1[r];
        #pragma unroll
        for (int off = 1; off < 16; off <<= 1) {
          sv += __shfl_xor(sv, off, 64);
          qv += __shfl_xor(qv, off, 64);
        }
        if (col == 0) {
          float* dst = ps + (((size_t)p * 16 + bloc + r) * 32 + beta) * 4;
          store_coh_f32_tag(dst, sv, tag);       // [s | tag]
          store_coh_f32_tag(dst + 2, qv, tag);   // [q | tag]
        }
      }
      // w(t+1) prefetch into SEPARATE regs; latency hides under the gather-poll
      {
        int tn = t < 999 ? t + 1 : t;
        #pragma unroll
        for (int r = 0; r < 4; ++r) {
          const u16* wr = w + ((size_t)(d * 16 + bloc + r) * 1000 + tn) * 2048 + ja;
          wn_a0[r] = wr[0]; wn_a1[r] = wr[16]; wn_z0[r] = wr[1024]; wn_z1[r] = wr[1040];
        }
      }
      // ---- R1 poll-gather: batches bloc..bloc+3 x blocks {col, col+16} ----
      float4v g[8];
      const float* rb = ps + ((size_t)p * 16 + bloc) * 128 + col * 4;
      int ok;
      do {
        asm volatile(
            "global_load_dwordx4 %0, %8, off sc0 sc1\n\t"
            "global_load_dwordx4 %1, %8, off offset:256  sc0 sc1\n\t"
            "global_load_dwordx4 %2, %8, off offset:512  sc0 sc1\n\t"
            "global_load_dwordx4 %3, %8, off offset:768  sc0 sc1\n\t"
            "global_load_dwordx4 %4, %8, off offset:1024 sc0 sc1\n\t"
            "global_load_dwordx4 %5, %8, off offset:1280 sc0 sc1\n\t"
            "global_load_dwordx4 %6, %8, off offset:1536 sc0 sc1\n\t"
            "global_load_dwordx4 %7, %8, off offset:1792 sc0 sc1\n\t"
            "s_waitcnt vmcnt(0)"
            : "=v"(g[0]), "=v"(g[1]), "=v"(g[2]), "=v"(g[3]),
              "=v"(g[4]), "=v"(g[5]), "=v"(g[6]), "=v"(g[7])
            : "v"(rb)
            : "memory");
        int okl = 1;
        #pragma unroll
        for (int i = 0; i < 8; ++i)
          okl &= (__float_as_uint(g[i][1]) == tag && __float_as_uint(g[i][3]) == tag) ? 1 : 0;
        ok = __all(okl);
      } while (!ok);

      // ---- LN + gates + h update (consumes wa* = w(t)) ----
      #pragma unroll
      for (int r = 0; r < 4; ++r) {
        float sm = g[2 * r][0] + g[2 * r + 1][0];
        float sq = g[2 * r][2] + g[2 * r + 1][2];
        #pragma unroll
        for (int off = 1; off < 16; off <<= 1) {
          sm += __shfl_xor(sm, off, 64);
          sq += __shfl_xor(sq, off, 64);
        }
        float mean = sm * (1.f / 2048.f);
        float var = sq * (1.f / 2048.f) - mean * mean;
        float inv = rsqrtf(var + 1e-5f);
        float ga0 = h2f(wa0[r]) * ssA0.x + ssA0.y + (aA0[r] - mean) * inv;
        float ga1 = h2f(wa1[r]) * ssA1.x + ssA1.y + (aA1[r] - mean) * inv;
        float gz0 = h2f(wz0[r]) * ssZ0.x + ssZ0.y + (aZ0[r] - mean) * inv;
        float gz1 = h2f(wz1[r]) * ssZ1.x + ssZ1.y + (aZ1[r] - mean) * inv;
        float z0 = 1.f / (1.f + __expf(-gz0));
        float z1 = 1.f / (1.f + __expf(-gz1));
        float h0 = z0 * hreg[r][0] + (1.f - z0) * (ga0 > 0.f ? ga0 : 0.f);
        float h1 = z1 * hreg[r][1] + (1.f - z1) * (ga1 > 0.f ? ga1 : 0.f);
        hreg[r][0] = h0; hreg[r][1] = h1;
        u16* hp = hb + (size_t)(bloc + r) * 1024 + ja;
        store_coh_u16(hp, (unsigned)f2h(h0));
        store_coh_u16(hp + 16, (unsigned)f2h(h1));
      }
      // rotate w regs: wa* <- wn* (w(t+1) for next iteration)
      #pragma unroll
      for (int r = 0; r < 4; ++r) {
        wa0[r] = wn_a0[r]; wa1[r] = wn_a1[r];
        wz0[r] = wn_z0[r]; wz1[r] = wn_z1[r];
      }
    }
    // ---- per-wave ack + flag: h stores of THIS wave globally visible ----
    asm volatile("s_waitcnt vmcnt(0)" ::: "memory");
    if (lane == 0) store_coh_u32(f2 + (size_t)beta * 16 + kh, tag);
    // output stores: plain (non-coherent), drain under the poll below
    if (act) {
      #pragma unroll
      for (int r = 0; r < 4; ++r) {
        size_t orow = ((size_t)(d * 16 + bloc + r) * 1000 + t) * 1024 + ja;
        if (OUT_F32) { out32[orow] = hreg[r][0]; out32[orow + 16] = hreg[r][1]; }
        else         { out16[orow] = f2h(hreg[r][0]); out16[orow + 16] = f2h(hreg[r][1]); }
      }
    }
    // ---- R2 poll: every wave polls all 32 blocks x 4 wave-flags ----
    {
      uint4 v; int ok;
      do {
        if (lane < 32)
          asm volatile("global_load_dwordx4 %0, %1, off sc0 sc1\n\ts_waitcnt vmcnt(0)"
                       : "=v"(v) : "v"(f2 + (size_t)lane * 16) : "memory");
        ok = __all(lane < 32 ? (int)(v.x >= tag && v.y >= tag && v.z >= tag && v.w >= tag) : 1);
      } while (!ok);
    }
  }
}

extern "C" void kernel_launch(void* const* d_in, const int* in_sizes, int n_in,
                              void* d_out, int out_size, void* d_ws, size_t ws_size,
                              hipStream_t stream) {
  (void)in_sizes; (void)n_in; (void)out_size;
  const float* x  = (const float*)d_in[0];
  const float* W1 = (const float*)d_in[1];
  const float* U1 = (const float*)d_in[2];
  const float* g1 = (const float*)d_in[3];
  const float* b1 = (const float*)d_in[4];
  const float* W2 = (const float*)d_in[5];
  const float* U2 = (const float*)d_in[6];
  const float* g2 = (const float*)d_in[7];
  const float* b2 = (const float*)d_in[8];

  char* ws = (char*)d_ws;
  size_t o = 0;
  auto take = [&](size_t bytes) { size_t r = o; o = (o + bytes + 255) & ~(size_t)255; return r; };
  u16* wbuf  = (u16*)(ws + take(32000ULL * 2048 * 2));   // 131 MB, reused by both layers
  u16* h1seq = (u16*)(ws + take(32000ULL * 1024 * 2));   // 65 MB layer-1 output (fp16)
  u16* xb    = (u16*)(ws + take(32000ULL * 80 * 2));
  u16* W1b   = (u16*)(ws + take(2048ULL * 80 * 2));
  u16* W2b   = (u16*)(ws + take(2048ULL * 1024 * 2));
  u16* U1b   = (u16*)(ws + take(2048ULL * 1024 * 2));
  u16* U2b   = (u16*)(ws + take(2048ULL * 1024 * 2));
  float2* ss1 = (float2*)(ws + take(2048 * 8));
  float2* ss2 = (float2*)(ws + take(2048 * 8));
  size_t zbase = o;  // everything below must start zeroed
  float* acc1 = (float*)(ws + take(2048 * 8));
  float* acc2 = (float*)(ws + take(2048 * 8));
  float* pstats1 = (float*)(ws + take(2ULL * 2 * 16 * 32 * 4 * 4));   // 32 KB
  float* pstats2 = (float*)(ws + take(2ULL * 2 * 16 * 32 * 4 * 4));
  unsigned* flags1 = (unsigned*)(ws + take(2ULL * 32 * 16 * 4));      // 4 KB
  unsigned* flags2 = (unsigned*)(ws + take(2ULL * 32 * 16 * 4));
  u16* hbuf1 = (u16*)(ws + take(32 * 1024 * 2));
  u16* hbuf2 = (u16*)(ws + take(32 * 1024 * 2));
  size_t zlen = o - zbase;
  if (ws_size < o) return;

  (void)hipMemsetAsync(ws + zbase, 0, zlen, stream);

  cvt_f32_f16<<<1280, 256, 0, stream>>>(x, xb, 32000 * 80);
  cvt_f32_f16<<<160, 256, 0, stream>>>(W1, W1b, 2048 * 80);
  cvt_f32_f16<<<1024, 256, 0, stream>>>(U1, U1b, 2048 * 1024);
  cvt_f32_f16<<<1024, 256, 0, stream>>>(W2, W2b, 2048 * 1024);
  cvt_f32_f16<<<1024, 256, 0, stream>>>(U2, U2b, 2048 * 1024);

  // ---- layer 1 ----
  gemm_f16<<<dim3(16, 250), 256, 0, stream>>>(xb, W1b, wbuf, 80);
  bn_stats<<<dim3(8, 125), 256, 0, stream>>>(wbuf, acc1);
  bn_final<<<8, 256, 0, stream>>>(acc1, g1, b1, ss1);
  rec_kernel<0><<<64, 256, 0, stream>>>(wbuf, ss1, U1b, hbuf1, pstats1, flags1, h1seq, nullptr);

  // ---- layer 2 ----
  gemm_f16<<<dim3(16, 250), 256, 0, stream>>>(h1seq, W2b, wbuf, 1024);
  bn_stats<<<dim3(8, 125), 256, 0, stream>>>(wbuf, acc2);
  bn_final<<<8, 256, 0, stream>>>(acc2, g2, b2, ss2);
  rec_kernel<1><<<64, 256, 0, stream>>>(wbuf, ss2, U2b, hbuf2, pstats2, flags2, nullptr, (float*)d_out);
}

// Round 7
// 15995.003 us; speedup vs baseline: 1.1367x; 1.1367x over previous
//
#include <hip/hip_runtime.h>

typedef unsigned short u16;
typedef _Float16 f16;
typedef f16 half8 __attribute__((ext_vector_type(8)));
typedef float float4v __attribute__((ext_vector_type(4)));

union HV { uint4 u; half8 h; u16 s[8]; };

__device__ __forceinline__ float h2f(u16 u) { union { u16 u; f16 h; } c; c.u = u; return (float)c.h; }
__device__ __forceinline__ u16 f2h(float f) { union { u16 u; f16 h; } c; c.h = (f16)f; return c.u; }

// ---- coherent (cross-XCD) access helpers: sc0 sc1 => operate at LLC, bypass XCD L2 ----
__device__ __forceinline__ void store_coh_u16(u16* p, unsigned v) {
  asm volatile("global_store_short %0, %1, off sc0 sc1" :: "v"(p), "v"(v) : "memory");
}
__device__ __forceinline__ void store_coh_u32(void* p, unsigned v) {
  asm volatile("global_store_dword %0, %1, off sc0 sc1" :: "v"(p), "v"(v) : "memory");
}
// single-instruction 8B store: [f32 payload | u32 epoch tag] — atomically visible
__device__ __forceinline__ void store_coh_f32_tag(float* p, float val, unsigned tag) {
  unsigned long long pk = (unsigned long long)__float_as_uint(val) |
                          ((unsigned long long)tag << 32);
  asm volatile("global_store_dwordx2 %0, %1, off sc0 sc1" :: "v"(p), "v"(pk) : "memory");
}

// ---------------- fp32 -> fp16 convert ----------------
__global__ void cvt_f32_f16(const float* __restrict__ s, u16* __restrict__ d, int n) {
  for (int i = blockIdx.x * blockDim.x + threadIdx.x; i < n; i += gridDim.x * blockDim.x)
    d[i] = f2h(s[i]);
}

// ---------------- GEMM: C[M][2048] = A[M][K] * B[2048][K]^T (fp16 in/out, fp32 accum) ----------
__global__ __launch_bounds__(256) void gemm_f16(const u16* __restrict__ A, const u16* __restrict__ B,
                                                u16* __restrict__ C, int K) {
  __shared__ u16 As[128][40];
  __shared__ u16 Bs[128][40];
  const int tid = threadIdx.x, lane = tid & 63, wid = tid >> 6;
  const int col = lane & 15, quad = lane >> 4;
  const int wm = (wid & 1) * 64, wn = (wid >> 1) * 64;
  const int n0 = blockIdx.x * 128;
  const int m0 = blockIdx.y * 128;
  float4v acc[4][4];
  #pragma unroll
  for (int i = 0; i < 4; ++i)
    #pragma unroll
    for (int j = 0; j < 4; ++j) acc[i][j] = (float4v){0.f, 0.f, 0.f, 0.f};

  const int srow = tid >> 2;
  const int schunk = (tid & 3) * 8;

  for (int k0 = 0; k0 < K; k0 += 32) {
    __syncthreads();
    #pragma unroll
    for (int r2 = 0; r2 < 2; ++r2) {
      int row = srow + 64 * r2;
      int kk = k0 + schunk;
      uint4 av = {0, 0, 0, 0}, bv = {0, 0, 0, 0};
      if (kk + 8 <= K) {
        av = *(const uint4*)(A + (size_t)(m0 + row) * K + kk);
        bv = *(const uint4*)(B + (size_t)(n0 + row) * K + kk);
      }
      *(uint4*)&As[row][schunk] = av;
      *(uint4*)&Bs[row][schunk] = bv;
    }
    __syncthreads();
    HV af[4], bf[4];
    #pragma unroll
    for (int i = 0; i < 4; ++i) af[i].u = *(const uint4*)&As[wm + i * 16 + col][quad * 8];
    #pragma unroll
    for (int j = 0; j < 4; ++j) bf[j].u = *(const uint4*)&Bs[wn + j * 16 + col][quad * 8];
    #pragma unroll
    for (int i = 0; i < 4; ++i)
      #pragma unroll
      for (int j = 0; j < 4; ++j)
        acc[i][j] = __builtin_amdgcn_mfma_f32_16x16x32_f16(af[i].h, bf[j].h, acc[i][j], 0, 0, 0);
  }
  #pragma unroll
  for (int i = 0; i < 4; ++i)
    #pragma unroll
    for (int j = 0; j < 4; ++j)
      #pragma unroll
      for (int r = 0; r < 4; ++r) {
        int m = m0 + wm + i * 16 + quad * 4 + r;
        int n = n0 + wn + j * 16 + col;
        C[(size_t)m * 2048 + n] = f2h(acc[i][j][r]);
      }
}

// ---------------- BatchNorm stats over 32000 rows ----------------
__global__ void bn_stats(const u16* __restrict__ C, float* __restrict__ acc) {
  int c = blockIdx.x * 256 + threadIdx.x;
  int r0 = blockIdx.y * 256;
  float s = 0.f, q = 0.f;
  for (int r = r0; r < r0 + 256; ++r) {
    float v = h2f(C[(size_t)r * 2048 + c]);
    s += v; q += v * v;
  }
  atomicAdd(&acc[2 * c], s);
  atomicAdd(&acc[2 * c + 1], q);
}

__global__ void bn_final(const float* __restrict__ acc, const float* __restrict__ g,
                         const float* __restrict__ b, float2* __restrict__ ss) {
  int c = blockIdx.x * 256 + threadIdx.x;
  float mean = acc[2 * c] * (1.f / 32000.f);
  float var = acc[2 * c + 1] * (1.f / 32000.f) - mean * mean;
  float sc = g[c] * rsqrtf(var + 1e-5f);
  float2 o; o.x = sc; o.y = b[c] - mean * sc;
  ss[c] = o;
}

// ---------------- persistent recurrence ----------------
// 2 independent domains x 16 blocks (32 blocks total; latency-bound => idle
// CUs are free). Domain d owns batches [16d,16d+16). Block beta owns 128 gate
// cols: a-cols [64b,64b+64), z-cols 1024+[64b,64b+64) — 4 col-groups of 16.
// Wave kh holds U K-slice [256kh,256kh+256) for all 128 cols in VGPRs
// (64 x uint4 = 256 VGPR; total ~430, 1 block/CU, launch_bounds(256,1)).
//
// r5 lesson: symmetric phase-B REGRESSED (more poll chains, more skew).
// Back to wave0-only phase B; the lever here is domain size 32 -> 16:
// halves barrier population, gather fan-in (4 loads), flag count (16).
//
// Per step: R1 stats via epoch-tagged 8B records (poll-gather, no flag, no
// ack); R2 h broadcast via per-block epoch flag (store-ack + flag + poll).
// w(t) is issued right after S1 and consumed ~1us later after the gather
// (HBM latency hidden; no double-buffer needed).
//
// Safety: stats(t) published after S1 => all 4 waves' h loads(t) drained =>
// h(t) stores race-free vs h(t-1) loads (single-buffer h safe). pstats
// parity slot reuse is 2 epochs behind any reader via the f2 round. LDS red:
// write(t) -> S1 -> wave0 read(t) -> f2 flag(t); waves 1-3 write red(t+1)
// only after passing the f2(t) poll.
//
// pstats: [dom][phase][batch16][block16][s,tag,q,tag] f32
// flags:  [dom][block16][16] u32
template <int OUT_F32>
__global__ __launch_bounds__(256, 1) void rec_kernel(
    const u16* __restrict__ w,      // [32*1000][2048] fp16 (pre-BN)
    const float2* __restrict__ ss,  // [2048] BN scale/shift
    const u16* __restrict__ U,      // [2048][1024] fp16
    u16* hbuf,                      // [32][1024] fp16 (current h)
    float* pstats,                  // [2][2][16][16][4] f32
    unsigned* flags,                // [2][16][16] u32
    u16* out16, float* out32) {
  const int tid = threadIdx.x, lane = tid & 63, kh = tid >> 6;
  const int d = blockIdx.x >> 4, beta = blockIdx.x & 15;
  const int col = lane & 15, quad = lane >> 4;
  __shared__ float4v red[3][8][64];

  const int A0 = beta * 64;           // a-col base; groups at +16g, z at +1024

  HV ufA[4][8], ufZ[4][8];            // U fragments: 128 gate cols x K=256
  #pragma unroll
  for (int g = 0; g < 4; ++g)
    #pragma unroll
    for (int kk = 0; kk < 8; ++kk) {
      int k = kh * 256 + kk * 32 + quad * 8;
      int ja = A0 + g * 16 + col;
      ufA[g][kk].u = *(const uint4*)(U + (size_t)ja * 1024 + k);
      ufZ[g][kk].u = *(const uint4*)(U + (size_t)(1024 + ja) * 1024 + k);
    }
  float2 ssA[4], ssZ[4];
  #pragma unroll
  for (int g = 0; g < 4; ++g) {
    ssA[g] = ss[A0 + g * 16 + col];
    ssZ[g] = ss[1024 + A0 + g * 16 + col];
  }

  u16* hb = hbuf + (size_t)d * 16 * 1024;          // this domain's 16 h rows
  float* ps = pstats + (size_t)d * 2048;           // 2*16*16*4 floats
  unsigned* f2 = flags + (size_t)d * 256;          // 16 x 16 u32 (64B stride)

  const u16* aptr = hb + (size_t)col * 1024 + kh * 256 + quad * 8;
  const int bloc = quad * 4;                       // phase-B batch group

  float hreg[4][4] = {};                           // [r][g]

  for (int t = 0; t < 1000; ++t) {
    const unsigned tag = (unsigned)t + 1u;
    // ---- phase A: coherent h load (8 x 16B) + partial-K MFMA ----
    HV af[8];
    asm volatile(
        "global_load_dwordx4 %0, %8, off sc0 sc1\n\t"
        "global_load_dwordx4 %1, %8, off offset:64  sc0 sc1\n\t"
        "global_load_dwordx4 %2, %8, off offset:128 sc0 sc1\n\t"
        "global_load_dwordx4 %3, %8, off offset:192 sc0 sc1\n\t"
        "global_load_dwordx4 %4, %8, off offset:256 sc0 sc1\n\t"
        "global_load_dwordx4 %5, %8, off offset:320 sc0 sc1\n\t"
        "global_load_dwordx4 %6, %8, off offset:384 sc0 sc1\n\t"
        "global_load_dwordx4 %7, %8, off offset:448 sc0 sc1\n\t"
        "s_waitcnt vmcnt(0)"
        : "=v"(af[0].u), "=v"(af[1].u), "=v"(af[2].u), "=v"(af[3].u),
          "=v"(af[4].u), "=v"(af[5].u), "=v"(af[6].u), "=v"(af[7].u)
        : "v"(aptr)
        : "memory");

    float4v aA[4], aZ[4];
    #pragma unroll
    for (int g = 0; g < 4; ++g) {
      aA[g] = (float4v){0.f, 0.f, 0.f, 0.f};
      aZ[g] = (float4v){0.f, 0.f, 0.f, 0.f};
    }
    #pragma unroll
    for (int kk = 0; kk < 8; ++kk)
      #pragma unroll
      for (int g = 0; g < 4; ++g) {
        aA[g] = __builtin_amdgcn_mfma_f32_16x16x32_f16(af[kk].h, ufA[g][kk].h, aA[g], 0, 0, 0);
        aZ[g] = __builtin_amdgcn_mfma_f32_16x16x32_f16(af[kk].h, ufZ[g][kk].h, aZ[g], 0, 0, 0);
      }
    if (kh) {
      #pragma unroll
      for (int g = 0; g < 4; ++g) {
        red[kh - 1][g][lane] = aA[g];
        red[kh - 1][4 + g][lane] = aZ[g];
      }
    }
    __syncthreads();   // S1: partials ready (all waves' h loads drained)

    if (kh == 0) {
      // w(t) loads issued NOW, consumed after the gather (~1us later)
      u16 wa[4][4], wz[4][4];
      #pragma unroll
      for (int r = 0; r < 4; ++r) {
        const u16* wr = w + ((size_t)(d * 16 + bloc + r) * 1000 + t) * 2048 + A0 + col;
        #pragma unroll
        for (int g = 0; g < 4; ++g) { wa[r][g] = wr[g * 16]; wz[r][g] = wr[1024 + g * 16]; }
      }
      #pragma unroll
      for (int s = 0; s < 3; ++s)
        #pragma unroll
        for (int g = 0; g < 4; ++g) {
          aA[g] += red[s][g][lane];
          aZ[g] += red[s][4 + g][lane];
        }
      const int p = t & 1;
      // ---- R1 publish: tagged per-batch partial stats over 128 cols ----
      #pragma unroll
      for (int r = 0; r < 4; ++r) {
        float sv = 0.f, qv = 0.f;
        #pragma unroll
        for (int g = 0; g < 4; ++g) {
          sv += aA[g][r] + aZ[g][r];
          qv += aA[g][r] * aA[g][r] + aZ[g][r] * aZ[g][r];
        }
        #pragma unroll
        for (int off = 1; off < 16; off <<= 1) {
          sv += __shfl_xor(sv, off, 64);
          qv += __shfl_xor(qv, off, 64);
        }
        if (col == 0) {
          float* dst = ps + (((size_t)p * 16 + bloc + r) * 16 + beta) * 4;
          store_coh_f32_tag(dst, sv, tag);       // [s | tag]
          store_coh_f32_tag(dst + 2, qv, tag);   // [q | tag]
        }
      }
      // ---- R1 poll-gather: batches bloc..bloc+3 x block `col` (16 blocks) ----
      float4v g4[4];
      const float* rb = ps + ((size_t)p * 16 + bloc) * 64 + col * 4;
      int ok;
      do {
        asm volatile(
            "global_load_dwordx4 %0, %4, off sc0 sc1\n\t"
            "global_load_dwordx4 %1, %4, off offset:256 sc0 sc1\n\t"
            "global_load_dwordx4 %2, %4, off offset:512 sc0 sc1\n\t"
            "global_load_dwordx4 %3, %4, off offset:768 sc0 sc1\n\t"
            "s_waitcnt vmcnt(0)"
            : "=v"(g4[0]), "=v"(g4[1]), "=v"(g4[2]), "=v"(g4[3])
            : "v"(rb)
            : "memory");
        int okl = 1;
        #pragma unroll
        for (int i = 0; i < 4; ++i)
          okl &= (__float_as_uint(g4[i][1]) == tag && __float_as_uint(g4[i][3]) == tag) ? 1 : 0;
        ok = __all(okl);
      } while (!ok);

      // ---- LN + gates + h update ----
      #pragma unroll
      for (int r = 0; r < 4; ++r) {
        float sm = g4[r][0];
        float sq = g4[r][2];
        #pragma unroll
        for (int off = 1; off < 16; off <<= 1) {
          sm += __shfl_xor(sm, off, 64);
          sq += __shfl_xor(sq, off, 64);
        }
        float mean = sm * (1.f / 2048.f);
        float var = sq * (1.f / 2048.f) - mean * mean;
        float inv = rsqrtf(var + 1e-5f);
        #pragma unroll
        for (int g = 0; g < 4; ++g) {
          float ga = h2f(wa[r][g]) * ssA[g].x + ssA[g].y + (aA[g][r] - mean) * inv;
          float gz = h2f(wz[r][g]) * ssZ[g].x + ssZ[g].y + (aZ[g][r] - mean) * inv;
          float z = 1.f / (1.f + __expf(-gz));
          float h = z * hreg[r][g] + (1.f - z) * (ga > 0.f ? ga : 0.f);
          hreg[r][g] = h;
          store_coh_u16(hb + (size_t)(bloc + r) * 1024 + A0 + g * 16 + col, (unsigned)f2h(h));
        }
      }
      asm volatile("s_waitcnt vmcnt(0)" ::: "memory");   // h ack
      if (lane == 0) store_coh_u32(f2 + (size_t)beta * 16, tag);
      // output stores: plain (non-coherent), drain under the f2 poll
      #pragma unroll
      for (int r = 0; r < 4; ++r) {
        size_t orow = ((size_t)(d * 16 + bloc + r) * 1000 + t) * 1024 + A0 + col;
        #pragma unroll
        for (int g = 0; g < 4; ++g) {
          if (OUT_F32) out32[orow + g * 16] = hreg[r][g];
          else         out16[orow + g * 16] = f2h(hreg[r][g]);
        }
      }
    }
    // ---- R2 poll: all 4 waves poll the 16 f2 flags (lanes<16) ----
    {
      unsigned fv = tag; int ok;
      do {
        if (lane < 16)
          asm volatile("global_load_dword %0, %1, off sc0 sc1\n\ts_waitcnt vmcnt(0)"
                       : "=v"(fv) : "v"(f2 + (size_t)lane * 16) : "memory");
        ok = __all(lane < 16 ? (int)(fv >= tag) : 1);
      } while (!ok);
    }
  }
}

extern "C" void kernel_launch(void* const* d_in, const int* in_sizes, int n_in,
                              void* d_out, int out_size, void* d_ws, size_t ws_size,
                              hipStream_t stream) {
  (void)in_sizes; (void)n_in; (void)out_size;
  const float* x  = (const float*)d_in[0];
  const float* W1 = (const float*)d_in[1];
  const float* U1 = (const float*)d_in[2];
  const float* g1 = (const float*)d_in[3];
  const float* b1 = (const float*)d_in[4];
  const float* W2 = (const float*)d_in[5];
  const float* U2 = (const float*)d_in[6];
  const float* g2 = (const float*)d_in[7];
  const float* b2 = (const float*)d_in[8];

  char* ws = (char*)d_ws;
  size_t o = 0;
  auto take = [&](size_t bytes) { size_t r = o; o = (o + bytes + 255) & ~(size_t)255; return r; };
  u16* wbuf  = (u16*)(ws + take(32000ULL * 2048 * 2));   // 131 MB, reused by both layers
  u16* h1seq = (u16*)(ws + take(32000ULL * 1024 * 2));   // 65 MB layer-1 output (fp16)
  u16* xb    = (u16*)(ws + take(32000ULL * 80 * 2));
  u16* W1b   = (u16*)(ws + take(2048ULL * 80 * 2));
  u16* W2b   = (u16*)(ws + take(2048ULL * 1024 * 2));
  u16* U1b   = (u16*)(ws + take(2048ULL * 1024 * 2));
  u16* U2b   = (u16*)(ws + take(2048ULL * 1024 * 2));
  float2* ss1 = (float2*)(ws + take(2048 * 8));
  float2* ss2 = (float2*)(ws + take(2048 * 8));
  size_t zbase = o;  // everything below must start zeroed
  float* acc1 = (float*)(ws + take(2048 * 8));
  float* acc2 = (float*)(ws + take(2048 * 8));
  float* pstats1 = (float*)(ws + take(2ULL * 2 * 16 * 16 * 4 * 4));   // 16 KB
  float* pstats2 = (float*)(ws + take(2ULL * 2 * 16 * 16 * 4 * 4));
  unsigned* flags1 = (unsigned*)(ws + take(2ULL * 16 * 16 * 4));      // 2 KB
  unsigned* flags2 = (unsigned*)(ws + take(2ULL * 16 * 16 * 4));
  u16* hbuf1 = (u16*)(ws + take(32 * 1024 * 2));
  u16* hbuf2 = (u16*)(ws + take(32 * 1024 * 2));
  size_t zlen = o - zbase;
  if (ws_size < o) return;

  (void)hipMemsetAsync(ws + zbase, 0, zlen, stream);

  cvt_f32_f16<<<1280, 256, 0, stream>>>(x, xb, 32000 * 80);
  cvt_f32_f16<<<160, 256, 0, stream>>>(W1, W1b, 2048 * 80);
  cvt_f32_f16<<<1024, 256, 0, stream>>>(U1, U1b, 2048 * 1024);
  cvt_f32_f16<<<1024, 256, 0, stream>>>(W2, W2b, 2048 * 1024);
  cvt_f32_f16<<<1024, 256, 0, stream>>>(U2, U2b, 2048 * 1024);

  // ---- layer 1 ----
  gemm_f16<<<dim3(16, 250), 256, 0, stream>>>(xb, W1b, wbuf, 80);
  bn_stats<<<dim3(8, 125), 256, 0, stream>>>(wbuf, acc1);
  bn_final<<<8, 256, 0, stream>>>(acc1, g1, b1, ss1);
  rec_kernel<0><<<32, 256, 0, stream>>>(wbuf, ss1, U1b, hbuf1, pstats1, flags1, h1seq, nullptr);

  // ---- layer 2 ----
  gemm_f16<<<dim3(16, 250), 256, 0, stream>>>(h1seq, W2b, wbuf, 1024);
  bn_stats<<<dim3(8, 125), 256, 0, stream>>>(wbuf, acc2);
  bn_final<<<8, 256, 0, stream>>>(acc2, g2, b2, ss2);
  rec_kernel<1><<<32, 256, 0, stream>>>(wbuf, ss2, U2b, hbuf2, pstats2, flags2, nullptr, (float*)d_out);
}